// Round 18
// baseline (65.876 us; speedup 1.0000x reference)
//
#include <hip/hip_runtime.h>

// DMV inside — linear-domain sum-product, paired spans, WIDTH-ADAPTIVE GROUPS.
// One block per batch item, 512 threads. Group g owns span (h=g, e=h+w), both
// direction cells. Group size LG adapts to width:
//   cd > 32 (w <= 31): LG=8,  64 groups, NJ=ceil(w/8)  <= 4
//   cd <= 32 (w >= nl-32): LG=16, 32 groups, NJ=ceil(w/16) <= 4
// Rationale (R17 PMC): latency-bound per barrier-step (~500cyc chain, VALUBusy
// 43%, occ 68%); at large w most lanes idle while chains lengthen. LG=16 for
// the large-w half halves the serial j-chain exactly where lanes are free
// (sum NJ per block 287 -> 166). Boundary invariant LG*(NJ-1) <= w-1 holds for
// any LG since NJ=ceil(w/LG).
//  - Linear charts F''=exp2(F+ALPHA*width) (R16, absmax 0.0); pairing shares
//    phase-A loads+fma between the span's two cells (R17).
//  - Select-AFTER-compute masks garbage/NaN; width-w values used via regs.
//  - 8/16-lane DPP reduce (xor1, xor2, half_mirror(0x141) [, mirror(0x140)]).
//  - 4 blocks/CU, 32 waves/CU; counting-sort + quartile-snake balance (R7).
//  - Spill sentinel: WRITE_SIZE ~22KB (MB-scale => scratch, revert to R17).

#define NEGV   -1000000000.0f
#define NMAX   64
#define LDS_S  69
#define BLOCK  512
#define ALPHA  8.0f

#if __has_builtin(__builtin_amdgcn_exp2f)
#define EXP2F(x) __builtin_amdgcn_exp2f(x)
#else
#define EXP2F(x) __expf((x) * 0.6931471805599453f)
#endif
#if __has_builtin(__builtin_amdgcn_logf)
#define LOG2F(x) __builtin_amdgcn_logf(x)
#else
#define LOG2F(x) (__logf(x) * 1.4426950408889634f)
#endif
#define LOG2E 1.4426950408889634f
#define LN2   0.6931471805599453f

template<int CTRL>
__device__ __forceinline__ float dppf(float v) {
    return __int_as_float(__builtin_amdgcn_update_dpp(
        0, __float_as_int(v), CTRL, 0xF, 0xF, true));
}
template<int LG>
__device__ __forceinline__ float grp_sum(float s) {
    s += dppf<0xB1>(s);                      // quad_perm xor 1
    s += dppf<0x4E>(s);                      // quad_perm xor 2
    s += dppf<0x141>(s);                     // row_half_mirror: 8-lane sum
    if constexpr (LG == 16) s += dppf<0x140>(s);   // row_mirror: 16-lane sum
    return s;
}

// ---- pre-kernel: counting sort by length (descending) + quartile-snake map ----
__global__ void order_kernel(const int* __restrict__ len_arr,
                             int* __restrict__ blk2item, int B)
{
    __shared__ int hist[33];
    __shared__ int base[33];
    const int tid = threadIdx.x;
    if (tid < 33) hist[tid] = 0;
    __syncthreads();
    int bin = 0;
    if (tid < B) {
        bin = 64 - len_arr[tid];          // 0 = longest
        atomicAdd(&hist[bin], 1);
    }
    __syncthreads();
    if (tid == 0) {
        int acc = 0;
        for (int i = 0; i < 33; ++i) { base[i] = acc; acc += hist[i]; }
    }
    __syncthreads();
    if (tid < B) {
        int rank = atomicAdd(&base[bin], 1);   // sorted-descending rank
        int j;
        if ((B & 255) == 0) {                   // snake across quartile stripes
            int q = rank >> 8, pos = rank & 255;
            j = (q & 1) ? ((q << 8) + 255 - pos) : ((q << 8) + pos);
        } else {
            j = rank;
        }
        blk2item[j] = tid;
    }
}

// Paired fused A+B step for span (h=gid, e=h+w). NJ, LG compile-time.
template<int NJ, int LG>
__device__ __forceinline__ void dmv_step(
    const int w, const int cd, const int tid,
    float* __restrict__ sI, float* __restrict__ sF,
    const float* __restrict__ goNCl, const float* __restrict__ goHMl,
    const float* __restrict__ stHCl, const float* __restrict__ stNCl,
    const int* __restrict__ th_s, const float* __restrict__ trans_param)
{
    constexpr int SH = (LG == 8) ? 3 : 4;
    const int gid = tid >> SH;
    const int lg  = tid & (LG - 1);
    if (gid >= cd) return;
    const int h = gid, e = h + w;

    const int thh = th_s[h], the = th_s[e];
    const float trlR = EXP2F(trans_param[(thh * NMAX + the) * 2 + 1] * LOG2E + ALPHA);
    const float trlL = EXP2F(trans_param[(the * NMAX + thh) * 2 + 0] * LOG2E + ALPHA);
    const float gncR = goNCl[NMAX + h], gmR = goHMl[NMAX + h];
    const float gncL = goNCl[e],        gmL = goHMl[e];
    const float dcR  = stNCl[NMAX + h];   // FR[h][h] width-0 diag
    const float dcL  = stNCl[e];          // FL[e][e]
    const float dcRe = stNCl[NMAX + e];   // FR[e][e] (B right endpoint)
    const float dcLh = stNCl[h];          // FL[h][h] (B left endpoint)

    // ---- phase A (shared streams): vF = FR[h][h+k], vC = FL[e][h+1+k] ----
    const int pF = h * LDS_S + h;        // +k
    const int pC = e * LDS_S + h + 1;    // +k
    float sInt = 0.f, bndR = 0.f, bndL = 0.f;
    #pragma unroll
    for (int j = 0; j < NJ; ++j) {
        const int k = lg + LG * j;
        if (j == NJ - 1) {                    // top boundary: clamp+mask+selects
            const int kc = (k < w) ? k : (w - 1);
            float vF = sF[pF + kc];
            float vC = sF[pC + kc];
            float tR = ((k == 0) ? gncR : vF * gmR) * ((k == w - 1) ? dcL : vC);
            float tL = ((k == w - 1) ? gncL : vC * gmL) * ((k == 0) ? dcR : vF);
            bndR += (k < w) ? tR : 0.f;       // select AFTER compute: kills NaN
            bndL += (k < w) ? tL : 0.f;
        } else if (j == 0) {                  // bottom boundary (k<=LG-1<=w-2)
            float vF = sF[pF + k];
            float vC = sF[pC + k];
            bndR += ((k == 0) ? gncR : vF * gmR) * vC;
            bndL += (vC * gmL) * ((k == 0) ? dcR : vF);
        } else {                              // interior: shared fma
            sInt = fmaf(sF[pF + k], sF[pC + k], sInt);
        }
    }
    const float aR = grp_sum<LG>(fmaf(gmR, sInt, bndR));
    const float aL = grp_sum<LG>(fmaf(gmL, sInt, bndL));
    const float irR = trlR * aR;              // group-uniform after DPP
    const float irL = trlL * aL;
    if (lg == 0) sI[h * LDS_S + e] = irR;
    if (lg == 1) sI[e * LDS_S + h] = irL;

    // ---- phase B (independent streams):
    // right: sum_k I_R[h][h+1+k] * F[h+1+k][e]  (k=w-1 -> irR*dcRe)
    // left:  sum_m I_L[e][h+m]   * F[h+m][h]    (m=0   -> irL*dcLh)
    const int pIR = h * LDS_S + h + 1;    // +k
    const int pGR = (h + 1) * LDS_S + e;  // +k*LDS_S
    const int pIL = e * LDS_S + h;        // +m
    const int pGL = h * LDS_S + h;        // +m*LDS_S
    float accR = 0.f, accL = 0.f;
    #pragma unroll
    for (int j = 0; j < NJ; ++j) {
        const int k = lg + LG * j;
        if (j == NJ - 1) {
            const int kc = (k < w) ? k : (w - 1);
            float i1 = sI[pIR + kc];
            float f1 = sF[pGR + kc * LDS_S];
            float i2 = sI[pIL + kc];
            float f2 = sF[pGL + kc * LDS_S];
            float tR = ((k == w - 1) ? irR : i1) * ((k == w - 1) ? dcRe : f1);
            float tL = ((k == 0) ? irL : i2) * ((k == 0) ? dcLh : f2);
            accR += (k < w) ? tR : 0.f;
            accL += (k < w) ? tL : 0.f;
        } else if (j == 0) {                  // k<=LG-1<w-1: right has no special
            float i1 = sI[pIR + k];
            float f1 = sF[pGR + k * LDS_S];
            float i2 = sI[pIL + k];
            float f2 = sF[pGL + k * LDS_S];
            accR = fmaf(i1, f1, accR);
            accL += ((k == 0) ? irL : i2) * ((k == 0) ? dcLh : f2);
        } else {
            accR = fmaf(sI[pIR + k], sF[pGR + k * LDS_S], accR);
            accL = fmaf(sI[pIL + k], sF[pGL + k * LDS_S], accL);
        }
    }
    const float bR = grp_sum<LG>(accR);
    const float bL = grp_sum<LG>(accL);
    if (lg == 0) sF[h * LDS_S + e] = stHCl[NMAX + h] * bR;
    if (lg == 1) sF[e * LDS_S + h] = stHCl[e] * bL;
}

__global__ __launch_bounds__(BLOCK, 8)
void dmv_inside_kernel(const int* __restrict__ tag,
                       const int* __restrict__ len_arr,
                       const float* __restrict__ root_param,
                       const float* __restrict__ trans_param,
                       const float* __restrict__ dec_param,
                       const int* __restrict__ blk2item,
                       float* __restrict__ out)
{
    __shared__ float sI[NMAX * LDS_S];     // I'' (linear, trend-scaled)
    __shared__ float sF[NMAX * LDS_S];     // F'' (linear, trend-scaled)
    __shared__ float goNCl[2 * NMAX];      // linear params; [0]=L, [1]=R
    __shared__ float goHMl[2 * NMAX];      // exp2(go_hc - st_hc)
    __shared__ float stHCl[2 * NMAX];
    __shared__ float stNCl[2 * NMAX];      // width-0 "diagonal" of F'' (shift 0)
    __shared__ float root_l[NMAX];         // linear root
    __shared__ int   th_s[NMAX];

    const int b   = blk2item[blockIdx.x];  // balanced assignment
    const int tid = threadIdx.x;
    const int nl  = len_arr[b];            // 32..64; output depends only on [0,nl)

    if (tid < NMAX) {
        int t = tag[b * NMAX + tid];
        th_s[tid] = t;
        const float* d = dec_param + t * 8;   // [dir][val][dec], L=0 R=1
        goNCl[0 * NMAX + tid] = EXP2F(d[0] * LOG2E);
        stNCl[0 * NMAX + tid] = EXP2F(d[1] * LOG2E);
        goHMl[0 * NMAX + tid] = EXP2F((d[2] - d[3]) * LOG2E);
        stHCl[0 * NMAX + tid] = EXP2F(d[3] * LOG2E);
        goNCl[1 * NMAX + tid] = EXP2F(d[4] * LOG2E);
        stNCl[1 * NMAX + tid] = EXP2F(d[5] * LOG2E);
        goHMl[1 * NMAX + tid] = EXP2F((d[6] - d[7]) * LOG2E);
        stHCl[1 * NMAX + tid] = EXP2F(d[7] * LOG2E);
        root_l[tid]           = EXP2F(root_param[t] * LOG2E);
    }
    __syncthreads();

    for (int w = 1; w < nl; ++w) {
        const int cd = nl - w;     // spans this step
        if (cd > 32) {             // w <= nl-33 <= 31: LG=8, 64 groups
            switch ((w - 1) >> 3) {
            case 0:  dmv_step<1, 8>(w, cd, tid, sI, sF, goNCl, goHMl, stHCl, stNCl, th_s, trans_param); break;
            case 1:  dmv_step<2, 8>(w, cd, tid, sI, sF, goNCl, goHMl, stHCl, stNCl, th_s, trans_param); break;
            case 2:  dmv_step<3, 8>(w, cd, tid, sI, sF, goNCl, goHMl, stHCl, stNCl, th_s, trans_param); break;
            default: dmv_step<4, 8>(w, cd, tid, sI, sF, goNCl, goHMl, stHCl, stNCl, th_s, trans_param); break;
            }
        } else {                   // cd <= 32: LG=16, 32 groups, w <= 63
            switch ((w - 1) >> 4) {
            case 0:  dmv_step<1, 16>(w, cd, tid, sI, sF, goNCl, goHMl, stHCl, stNCl, th_s, trans_param); break;
            case 1:  dmv_step<2, 16>(w, cd, tid, sI, sF, goNCl, goHMl, stHCl, stNCl, th_s, trans_param); break;
            case 2:  dmv_step<3, 16>(w, cd, tid, sI, sF, goNCl, goHMl, stHCl, stNCl, th_s, trans_param); break;
            default: dmv_step<4, 16>(w, cd, tid, sI, sF, goNCl, goHMl, stHCl, stNCl, th_s, trans_param); break;
            }
        }
        __syncthreads();
    }

    // ---- final (linear): out = ln2*(log2( sum_i root_l*FL''*FR'' ) - ALPHA*last)
    if (tid < 64) {
        const int last = nl - 1;
        float fl0 = (tid == 0)    ? stNCl[0 * NMAX + 0]    : sF[tid * LDS_S + 0];
        float fre = (tid == last) ? stNCl[1 * NMAX + last] : sF[tid * LDS_S + last];
        float xx  = (tid < nl) ? (root_l[tid] * fl0 * fre) : 0.f;  // select kills NaN
        #pragma unroll
        for (int off = 1; off < 64; off <<= 1)
            xx += __shfl_xor(xx, off, 64);
        if (tid == 0) out[b] = (LOG2F(xx) - ALPHA * last) * LN2;
    }
}

extern "C" void kernel_launch(void* const* d_in, const int* in_sizes, int n_in,
                              void* d_out, int out_size, void* d_ws, size_t ws_size,
                              hipStream_t stream) {
    // setup_inputs order: id_array, tag_array, len_array, root_param, trans_param, dec_param
    const int*   tag   = (const int*)d_in[1];
    const int*   len_a = (const int*)d_in[2];
    const float* root  = (const float*)d_in[3];
    const float* trans = (const float*)d_in[4];
    const float* dec   = (const float*)d_in[5];
    float* outp = (float*)d_out;
    const int B = in_sizes[2];   // 1024

    int* blk2item = (int*)d_ws;  // B ints

    int sortThreads = (B < 1024) ? ((B + 63) & ~63) : 1024;
    if (sortThreads < 64) sortThreads = 64;
    order_kernel<<<1, sortThreads, 0, stream>>>(len_a, blk2item, B);
    dmv_inside_kernel<<<B, BLOCK, 0, stream>>>(tag, len_a, root, trans, dec,
                                               blk2item, outp);
}

// Round 19
// 56.496 us; speedup vs baseline: 1.1660x; 1.1660x over previous
//
#include <hip/hip_runtime.h>

// DMV inside — linear-domain sum-product, paired spans, width-adaptive groups
// (CORRECTED GATE). One block per batch item, 512 threads. Group g owns span
// (h=g, e=h+w), both direction cells.
//   w <= 32: LG=8,  64 groups, NJ=ceil(w/8) <= 4   (proven R17 path)
//   w >= 33: LG=16, 32 groups, NJ=ceil(w/16) = 3..4 (halves serial chain)
// R18 ERRATUM: gating on cd<=32 routed MID/SMALL widths to LG=16 whenever
// nl<=~48, hitting the NJ=1-2 select-heavy boundary path for the bulk of the
// work (VALUBusy 43->57, dur 51->63). Gate on w: w>=33 => cd=nl-w<=31<32
// groups automatically, and NJ(LG8) would be 5-8 -> genuine chain halving.
// Invariants: NJ16=3 needs w>=33 (holds); NJ16=4 only for w>=49 (holds);
// j==0 slot needs w>=LG+1 (w>=33>17 holds).
//  - Linear charts F''=exp2(F+ALPHA*width) (R16); phase-A load+fma sharing
//    between the span's two cells (R17).
//  - Select-AFTER-compute masks garbage/NaN; width-w values via regs.
//  - 8/16-lane DPP reduce (xor1, xor2, half_mirror(0x141) [, mirror(0x140)]).
//  - 4 blocks/CU, 32 waves/CU; counting-sort + quartile-snake balance (R7).
//  - Spill sentinel: WRITE_SIZE ~22KB (MB-scale => scratch, revert to R17).

#define NEGV   -1000000000.0f
#define NMAX   64
#define LDS_S  69
#define BLOCK  512
#define ALPHA  8.0f

#if __has_builtin(__builtin_amdgcn_exp2f)
#define EXP2F(x) __builtin_amdgcn_exp2f(x)
#else
#define EXP2F(x) __expf((x) * 0.6931471805599453f)
#endif
#if __has_builtin(__builtin_amdgcn_logf)
#define LOG2F(x) __builtin_amdgcn_logf(x)
#else
#define LOG2F(x) (__logf(x) * 1.4426950408889634f)
#endif
#define LOG2E 1.4426950408889634f
#define LN2   0.6931471805599453f

template<int CTRL>
__device__ __forceinline__ float dppf(float v) {
    return __int_as_float(__builtin_amdgcn_update_dpp(
        0, __float_as_int(v), CTRL, 0xF, 0xF, true));
}
template<int LG>
__device__ __forceinline__ float grp_sum(float s) {
    s += dppf<0xB1>(s);                      // quad_perm xor 1
    s += dppf<0x4E>(s);                      // quad_perm xor 2
    s += dppf<0x141>(s);                     // row_half_mirror: 8-lane sum
    if constexpr (LG == 16) s += dppf<0x140>(s);   // row_mirror: 16-lane sum
    return s;
}

// ---- pre-kernel: counting sort by length (descending) + quartile-snake map ----
__global__ void order_kernel(const int* __restrict__ len_arr,
                             int* __restrict__ blk2item, int B)
{
    __shared__ int hist[33];
    __shared__ int base[33];
    const int tid = threadIdx.x;
    if (tid < 33) hist[tid] = 0;
    __syncthreads();
    int bin = 0;
    if (tid < B) {
        bin = 64 - len_arr[tid];          // 0 = longest
        atomicAdd(&hist[bin], 1);
    }
    __syncthreads();
    if (tid == 0) {
        int acc = 0;
        for (int i = 0; i < 33; ++i) { base[i] = acc; acc += hist[i]; }
    }
    __syncthreads();
    if (tid < B) {
        int rank = atomicAdd(&base[bin], 1);   // sorted-descending rank
        int j;
        if ((B & 255) == 0) {                   // snake across quartile stripes
            int q = rank >> 8, pos = rank & 255;
            j = (q & 1) ? ((q << 8) + 255 - pos) : ((q << 8) + pos);
        } else {
            j = rank;
        }
        blk2item[j] = tid;
    }
}

// Paired fused A+B step for span (h=gid, e=h+w). NJ, LG compile-time.
template<int NJ, int LG>
__device__ __forceinline__ void dmv_step(
    const int w, const int cd, const int tid,
    float* __restrict__ sI, float* __restrict__ sF,
    const float* __restrict__ goNCl, const float* __restrict__ goHMl,
    const float* __restrict__ stHCl, const float* __restrict__ stNCl,
    const int* __restrict__ th_s, const float* __restrict__ trans_param)
{
    constexpr int SH = (LG == 8) ? 3 : 4;
    const int gid = tid >> SH;
    const int lg  = tid & (LG - 1);
    if (gid >= cd) return;
    const int h = gid, e = h + w;

    const int thh = th_s[h], the = th_s[e];
    const float trlR = EXP2F(trans_param[(thh * NMAX + the) * 2 + 1] * LOG2E + ALPHA);
    const float trlL = EXP2F(trans_param[(the * NMAX + thh) * 2 + 0] * LOG2E + ALPHA);
    const float gncR = goNCl[NMAX + h], gmR = goHMl[NMAX + h];
    const float gncL = goNCl[e],        gmL = goHMl[e];
    const float dcR  = stNCl[NMAX + h];   // FR[h][h] width-0 diag
    const float dcL  = stNCl[e];          // FL[e][e]
    const float dcRe = stNCl[NMAX + e];   // FR[e][e] (B right endpoint)
    const float dcLh = stNCl[h];          // FL[h][h] (B left endpoint)

    // ---- phase A (shared streams): vF = FR[h][h+k], vC = FL[e][h+1+k] ----
    const int pF = h * LDS_S + h;        // +k
    const int pC = e * LDS_S + h + 1;    // +k
    float sInt = 0.f, bndR = 0.f, bndL = 0.f;
    #pragma unroll
    for (int j = 0; j < NJ; ++j) {
        const int k = lg + LG * j;
        if (j == NJ - 1) {                    // top boundary: clamp+mask+selects
            const int kc = (k < w) ? k : (w - 1);
            float vF = sF[pF + kc];
            float vC = sF[pC + kc];
            float tR = ((k == 0) ? gncR : vF * gmR) * ((k == w - 1) ? dcL : vC);
            float tL = ((k == w - 1) ? gncL : vC * gmL) * ((k == 0) ? dcR : vF);
            bndR += (k < w) ? tR : 0.f;       // select AFTER compute: kills NaN
            bndL += (k < w) ? tL : 0.f;
        } else if (j == 0) {                  // bottom boundary (k<=LG-1<=w-2)
            float vF = sF[pF + k];
            float vC = sF[pC + k];
            bndR += ((k == 0) ? gncR : vF * gmR) * vC;
            bndL += (vC * gmL) * ((k == 0) ? dcR : vF);
        } else {                              // interior: shared fma
            sInt = fmaf(sF[pF + k], sF[pC + k], sInt);
        }
    }
    const float aR = grp_sum<LG>(fmaf(gmR, sInt, bndR));
    const float aL = grp_sum<LG>(fmaf(gmL, sInt, bndL));
    const float irR = trlR * aR;              // group-uniform after DPP
    const float irL = trlL * aL;
    if (lg == 0) sI[h * LDS_S + e] = irR;
    if (lg == 1) sI[e * LDS_S + h] = irL;

    // ---- phase B (independent streams):
    // right: sum_k I_R[h][h+1+k] * F[h+1+k][e]  (k=w-1 -> irR*dcRe)
    // left:  sum_m I_L[e][h+m]   * F[h+m][h]    (m=0   -> irL*dcLh)
    const int pIR = h * LDS_S + h + 1;    // +k
    const int pGR = (h + 1) * LDS_S + e;  // +k*LDS_S
    const int pIL = e * LDS_S + h;        // +m
    const int pGL = h * LDS_S + h;        // +m*LDS_S
    float accR = 0.f, accL = 0.f;
    #pragma unroll
    for (int j = 0; j < NJ; ++j) {
        const int k = lg + LG * j;
        if (j == NJ - 1) {
            const int kc = (k < w) ? k : (w - 1);
            float i1 = sI[pIR + kc];
            float f1 = sF[pGR + kc * LDS_S];
            float i2 = sI[pIL + kc];
            float f2 = sF[pGL + kc * LDS_S];
            float tR = ((k == w - 1) ? irR : i1) * ((k == w - 1) ? dcRe : f1);
            float tL = ((k == 0) ? irL : i2) * ((k == 0) ? dcLh : f2);
            accR += (k < w) ? tR : 0.f;
            accL += (k < w) ? tL : 0.f;
        } else if (j == 0) {                  // k<=LG-1<w-1: right has no special
            float i1 = sI[pIR + k];
            float f1 = sF[pGR + k * LDS_S];
            float i2 = sI[pIL + k];
            float f2 = sF[pGL + k * LDS_S];
            accR = fmaf(i1, f1, accR);
            accL += ((k == 0) ? irL : i2) * ((k == 0) ? dcLh : f2);
        } else {
            accR = fmaf(sI[pIR + k], sF[pGR + k * LDS_S], accR);
            accL = fmaf(sI[pIL + k], sF[pGL + k * LDS_S], accL);
        }
    }
    const float bR = grp_sum<LG>(accR);
    const float bL = grp_sum<LG>(accL);
    if (lg == 0) sF[h * LDS_S + e] = stHCl[NMAX + h] * bR;
    if (lg == 1) sF[e * LDS_S + h] = stHCl[e] * bL;
}

__global__ __launch_bounds__(BLOCK, 8)
void dmv_inside_kernel(const int* __restrict__ tag,
                       const int* __restrict__ len_arr,
                       const float* __restrict__ root_param,
                       const float* __restrict__ trans_param,
                       const float* __restrict__ dec_param,
                       const int* __restrict__ blk2item,
                       float* __restrict__ out)
{
    __shared__ float sI[NMAX * LDS_S];     // I'' (linear, trend-scaled)
    __shared__ float sF[NMAX * LDS_S];     // F'' (linear, trend-scaled)
    __shared__ float goNCl[2 * NMAX];      // linear params; [0]=L, [1]=R
    __shared__ float goHMl[2 * NMAX];      // exp2(go_hc - st_hc)
    __shared__ float stHCl[2 * NMAX];
    __shared__ float stNCl[2 * NMAX];      // width-0 "diagonal" of F'' (shift 0)
    __shared__ float root_l[NMAX];         // linear root
    __shared__ int   th_s[NMAX];

    const int b   = blk2item[blockIdx.x];  // balanced assignment
    const int tid = threadIdx.x;
    const int nl  = len_arr[b];            // 32..64; output depends only on [0,nl)

    if (tid < NMAX) {
        int t = tag[b * NMAX + tid];
        th_s[tid] = t;
        const float* d = dec_param + t * 8;   // [dir][val][dec], L=0 R=1
        goNCl[0 * NMAX + tid] = EXP2F(d[0] * LOG2E);
        stNCl[0 * NMAX + tid] = EXP2F(d[1] * LOG2E);
        goHMl[0 * NMAX + tid] = EXP2F((d[2] - d[3]) * LOG2E);
        stHCl[0 * NMAX + tid] = EXP2F(d[3] * LOG2E);
        goNCl[1 * NMAX + tid] = EXP2F(d[4] * LOG2E);
        stNCl[1 * NMAX + tid] = EXP2F(d[5] * LOG2E);
        goHMl[1 * NMAX + tid] = EXP2F((d[6] - d[7]) * LOG2E);
        stHCl[1 * NMAX + tid] = EXP2F(d[7] * LOG2E);
        root_l[tid]           = EXP2F(root_param[t] * LOG2E);
    }
    __syncthreads();

    for (int w = 1; w < nl; ++w) {
        const int cd = nl - w;     // spans this step
        if (w <= 32) {             // proven R17 path: LG=8, 64 groups, NJ<=4
            switch ((w - 1) >> 3) {
            case 0:  dmv_step<1, 8>(w, cd, tid, sI, sF, goNCl, goHMl, stHCl, stNCl, th_s, trans_param); break;
            case 1:  dmv_step<2, 8>(w, cd, tid, sI, sF, goNCl, goHMl, stHCl, stNCl, th_s, trans_param); break;
            case 2:  dmv_step<3, 8>(w, cd, tid, sI, sF, goNCl, goHMl, stHCl, stNCl, th_s, trans_param); break;
            default: dmv_step<4, 8>(w, cd, tid, sI, sF, goNCl, goHMl, stHCl, stNCl, th_s, trans_param); break;
            }
        } else {                   // w>=33 => cd<=31: LG=16, 32 groups, NJ=3..4
            if (w <= 48)
                dmv_step<3, 16>(w, cd, tid, sI, sF, goNCl, goHMl, stHCl, stNCl, th_s, trans_param);
            else
                dmv_step<4, 16>(w, cd, tid, sI, sF, goNCl, goHMl, stHCl, stNCl, th_s, trans_param);
        }
        __syncthreads();
    }

    // ---- final (linear): out = ln2*(log2( sum_i root_l*FL''*FR'' ) - ALPHA*last)
    if (tid < 64) {
        const int last = nl - 1;
        float fl0 = (tid == 0)    ? stNCl[0 * NMAX + 0]    : sF[tid * LDS_S + 0];
        float fre = (tid == last) ? stNCl[1 * NMAX + last] : sF[tid * LDS_S + last];
        float xx  = (tid < nl) ? (root_l[tid] * fl0 * fre) : 0.f;  // select kills NaN
        #pragma unroll
        for (int off = 1; off < 64; off <<= 1)
            xx += __shfl_xor(xx, off, 64);
        if (tid == 0) out[b] = (LOG2F(xx) - ALPHA * last) * LN2;
    }
}

extern "C" void kernel_launch(void* const* d_in, const int* in_sizes, int n_in,
                              void* d_out, int out_size, void* d_ws, size_t ws_size,
                              hipStream_t stream) {
    // setup_inputs order: id_array, tag_array, len_array, root_param, trans_param, dec_param
    const int*   tag   = (const int*)d_in[1];
    const int*   len_a = (const int*)d_in[2];
    const float* root  = (const float*)d_in[3];
    const float* trans = (const float*)d_in[4];
    const float* dec   = (const float*)d_in[5];
    float* outp = (float*)d_out;
    const int B = in_sizes[2];   // 1024

    int* blk2item = (int*)d_ws;  // B ints

    int sortThreads = (B < 1024) ? ((B + 63) & ~63) : 1024;
    if (sortThreads < 64) sortThreads = 64;
    order_kernel<<<1, sortThreads, 0, stream>>>(len_a, blk2item, B);
    dmv_inside_kernel<<<B, BLOCK, 0, stream>>>(tag, len_a, root, trans, dec,
                                               blk2item, outp);
}